// Round 2
// baseline (3185.216 us; speedup 1.0000x reference)
//
#include <hip/hip_runtime.h>

// GrCNN: B=32, L=128, D=256, 127 sequential levels.
// Round 2: single persistent cooperative kernel. 256 blocks = (b, g):
// sentence b (0..31), col-group g (0..7, 32 central cols + shared gate tile).
// W slice staged in LDS once; sentence state lives in LDS, updated in place.
// Per level: 8 sibling blocks exchange changed cols via ping-pong global
// buffers + sentence-local device-scope barrier (gen counter = level).

#define B_ 32
#define L_ 128
#define D_ 256
#define K_ 512          // 2*D (left|right concat)
#define NG 8            // column groups
#define GC 32           // central cols per group
#define WC 48           // cols per group incl 16-col gate tile
#define NTHR 512        // 8 waves
#define LOG2E 1.4426950408889634f

typedef _Float16 half8 __attribute__((ext_vector_type(8)));
typedef float f32x4 __attribute__((ext_vector_type(4)));

// ---- prep: build WT[g][WC][K_] fp16 (col j -> 512 k's) ----
__global__ void prep_wt(const float* __restrict__ Wl, const float* __restrict__ Wr,
                        const float* __restrict__ Gl, const float* __restrict__ Gr,
                        _Float16* __restrict__ WT) {
    int g = blockIdx.x / WC;
    int j = blockIdx.x % WC;
    for (int k = threadIdx.x; k < K_; k += 256) {
        float v;
        if (j < GC) {
            int c = g * GC + j;
            v = (k < D_) ? Wl[k * D_ + c] : Wr[(k - D_) * D_ + c];
        } else {
            int jj = j - GC;
            v = 0.f;
            if (jj < 3) v = (k < D_) ? Gl[k * 3 + jj] : Gr[(k - D_) * 3 + jj];
        }
        WT[((size_t)(g * WC + j)) * K_ + k] = (_Float16)v;
    }
}

// ---- init: x -> fp16 state S0, level-0 col max, zero barriers ----
__global__ void init_state(const float* __restrict__ x, _Float16* __restrict__ S0,
                           float* __restrict__ out, int* __restrict__ bar) {
    int b = blockIdx.x;
    int c = threadIdx.x;  // 256
    if (b == 0 && c < 2 * B_) bar[c * 32] = 0;   // cnt[0..31], gen[0..31]
    float m = -3.4e38f;
    for (int l = 0; l < L_; ++l) {
        float v = x[((size_t)b * L_ + l) * D_ + c];
        S0[((size_t)b * L_ + l) * D_ + c] = (_Float16)v;
        m = fmaxf(m, v);
    }
    out[(size_t)b * L_ * D_ + c] = m;  // out[b][0][c]
}

// LDS: state 129 rows * 512B (swizzled) + W slice 48KB (swizzled) + wave maxes
#define SST_BYTES ((L_ + 1) * D_ * 2)     // 66048
#define WST_BYTES (WC * K_ * 2)           // 49152
#define LDS_BYTES (SST_BYTES + WST_BYTES + 8 * GC * 4)

__global__ __launch_bounds__(NTHR) void grcnn_persist(
    _Float16* __restrict__ S0, _Float16* __restrict__ S1,
    const _Float16* __restrict__ WT, const float* __restrict__ Wb,
    const float* __restrict__ Gb, float* __restrict__ out, int* __restrict__ bar)
{
    __shared__ alignas(16) char lds[LDS_BYTES];
    char* sst = lds;
    char* wst = lds + SST_BYTES;
    float* lmax = (float*)(lds + SST_BYTES + WST_BYTES);  // [8][GC]

    const int tid = threadIdx.x;
    const int b = blockIdx.x & 31, g = blockIdx.x >> 5;  // siblings share blockIdx%8

    // stage W slice once
    const _Float16* wg = WT + (size_t)g * WC * K_;
    for (int ch = tid; ch < WC * K_ / 8; ch += NTHR) {
        int j = ch >> 6, kc = ch & 63;
        half8 v = *(const half8*)(wg + j * K_ + kc * 8);
        int off = j * 1024 + kc * 16;
        off ^= ((off >> 10) & 7) << 4;
        *(half8*)(wst + off) = v;
    }
    // stage full sentence state from S0
    const _Float16* sb0 = S0 + (size_t)b * L_ * D_;
    for (int ch = tid; ch < L_ * 32; ch += NTHR) {
        int row = ch >> 5, kc = ch & 31;
        half8 v = *(const half8*)(sb0 + row * D_ + kc * 8);
        int off = row * 512 + kc * 16;
        off ^= ((off >> 9) & 7) << 4;
        *(half8*)(sst + off) = v;
    }

    const int w = tid >> 6, l = tid & 63;
    const int lr = l & 15, q = l >> 4;
    const int r0 = w * 16;                 // wave's 16-row slab
    const float gb0 = Gb[0], gb1 = Gb[1], gb2 = Gb[2];
    const float wb0 = Wb[g * GC + lr];
    const float wb1 = Wb[g * GC + 16 + lr];
    int* cnt = bar + b * 32;
    int* gen = bar + (B_ + b) * 32;
    __syncthreads();

    for (int t = 0; t < L_ - 1; ++t) {
        const int n = (L_ - 1) - t;        // rows computed this level
        _Float16* snb = ((t & 1) ? S0 : S1) + (size_t)b * L_ * D_;  // write S[(t+1)&1]
        const bool active = (r0 < n);

        f32x4 acc0 = {}, acc1 = {}, acc2 = {};
        if (active) {
            #pragma unroll
            for (int s = 0; s < 16; ++s) {
                const int ko = s * 64 + q * 16;
                int aoff = (r0 + lr) * 512 + ko; aoff ^= ((aoff >> 9) & 7) << 4;
                half8 av = *(const half8*)(sst + aoff);
                const int sw = (lr & 7) << 4;
                half8 b0 = *(const half8*)(wst + ((lr * 1024 + ko) ^ sw));
                half8 b1 = *(const half8*)(wst + (((16 + lr) * 1024 + ko) ^ sw));
                half8 b2 = *(const half8*)(wst + (((32 + lr) * 1024 + ko) ^ sw));
                acc0 = __builtin_amdgcn_mfma_f32_16x16x32_f16(av, b0, acc0, 0, 0, 0);
                acc1 = __builtin_amdgcn_mfma_f32_16x16x32_f16(av, b1, acc1, 0, 0, 0);
                acc2 = __builtin_amdgcn_mfma_f32_16x16x32_f16(av, b2, acc2, 0, 0, 0);
            }
        }

        float vmax0 = -3.4e38f, vmax1 = -3.4e38f;
        _Float16 nh[4][2];
        bool wr[4] = {false, false, false, false};
        if (active) {
            #pragma unroll
            for (int r = 0; r < 4; ++r) {
                const int row = r0 + q * 4 + r;
                float p0 = __shfl(acc2[r], (l & 48) + 0, 64) + gb0;
                float p1 = __shfl(acc2[r], (l & 48) + 1, 64) + gb1;
                float p2 = __shfl(acc2[r], (l & 48) + 2, 64) + gb2;
                if (row < n) {
                    wr[r] = true;
                    float mg = fmaxf(fmaxf(p0, p1), p2);
                    float e0 = exp2f((p0 - mg) * LOG2E);
                    float e1 = exp2f((p1 - mg) * LOG2E);
                    float e2 = exp2f((p2 - mg) * LOG2E);
                    float inv = __builtin_amdgcn_rcpf(e0 + e1 + e2);
                    float g0 = e0 * inv, g1 = e1 * inv, g2 = e2 * inv;
                    {   // nt = 0
                        int c = g * GC + lr;
                        float pre = acc0[r] + wb0;
                        float ex = exp2f(pre * (2.f * LOG2E));
                        float ce = 1.f - 2.f * __builtin_amdgcn_rcpf(ex + 1.f);
                        int lo = row * 512 + c * 2;       lo ^= ((lo >> 9) & 7) << 4;
                        int ro = (row + 1) * 512 + c * 2; ro ^= ((ro >> 9) & 7) << 4;
                        float lv = (float)*(const _Float16*)(sst + lo);
                        float rv = (float)*(const _Float16*)(sst + ro);
                        float nx = g0 * lv + g1 * ce + g2 * rv;
                        nh[r][0] = (_Float16)nx;
                        vmax0 = fmaxf(vmax0, nx);
                    }
                    {   // nt = 1
                        int c = g * GC + 16 + lr;
                        float pre = acc1[r] + wb1;
                        float ex = exp2f(pre * (2.f * LOG2E));
                        float ce = 1.f - 2.f * __builtin_amdgcn_rcpf(ex + 1.f);
                        int lo = row * 512 + c * 2;       lo ^= ((lo >> 9) & 7) << 4;
                        int ro = (row + 1) * 512 + c * 2; ro ^= ((ro >> 9) & 7) << 4;
                        float lv = (float)*(const _Float16*)(sst + lo);
                        float rv = (float)*(const _Float16*)(sst + ro);
                        float nx = g0 * lv + g1 * ce + g2 * rv;
                        nh[r][1] = (_Float16)nx;
                        vmax1 = fmaxf(vmax1, nx);
                    }
                }
            }
        }

        __syncthreads();   // all old-state reads done before in-place update

        if (active) {
            #pragma unroll
            for (int r = 0; r < 4; ++r) if (wr[r]) {
                const int row = r0 + q * 4 + r;
                int c0 = g * GC + lr;
                int o0 = row * 512 + c0 * 2; o0 ^= ((o0 >> 9) & 7) << 4;
                *(_Float16*)(sst + o0) = nh[r][0];
                int o1 = row * 512 + (c0 + 16) * 2; o1 ^= ((o1 >> 9) & 7) << 4;
                *(_Float16*)(sst + o1) = nh[r][1];
            }
        }
        // col-max across the 4 q-groups
        vmax0 = fmaxf(vmax0, __shfl_xor(vmax0, 16, 64));
        vmax0 = fmaxf(vmax0, __shfl_xor(vmax0, 32, 64));
        vmax1 = fmaxf(vmax1, __shfl_xor(vmax1, 16, 64));
        vmax1 = fmaxf(vmax1, __shfl_xor(vmax1, 32, 64));
        if (l < 16) { lmax[w * GC + l] = vmax0; lmax[w * GC + 16 + l] = vmax1; }
        __syncthreads();

        if (tid < GC) {
            float m = lmax[tid];
            #pragma unroll
            for (int ww = 1; ww < 8; ++ww) m = fmaxf(m, lmax[ww * GC + tid]);
            out[((size_t)b * L_ + (t + 1)) * D_ + g * GC + tid] = m;
        }
        // own 32 cols, rows 0..n-1: LDS -> global (16B chunks)
        for (int ch = tid; ch < n * 4; ch += NTHR) {
            int row = ch >> 2, i = ch & 3;
            int off = row * 512 + g * 64 + i * 16;
            int so = off ^ (((off >> 9) & 7) << 4);
            *(half8*)((char*)snb + off) = *(const half8*)(sst + so);
        }
        __syncthreads();   // drains vmcnt before the leader's fence

        if (tid == 0) {
            __threadfence();
            int prev = __hip_atomic_fetch_add(cnt, 1, __ATOMIC_ACQ_REL, __HIP_MEMORY_SCOPE_AGENT);
            if (prev == NG - 1) {
                __hip_atomic_store(cnt, 0, __ATOMIC_RELAXED, __HIP_MEMORY_SCOPE_AGENT);
                __hip_atomic_fetch_add(gen, 1, __ATOMIC_RELEASE, __HIP_MEMORY_SCOPE_AGENT);
            } else {
                while (__hip_atomic_load(gen, __ATOMIC_ACQUIRE, __HIP_MEMORY_SCOPE_AGENT) <= t)
                    __builtin_amdgcn_s_sleep(1);
            }
            __threadfence();
        }
        __syncthreads();

        // re-stage rows 0..n-1 (all 256 cols) from the just-written buffer
        for (int ch = tid; ch < n * 32; ch += NTHR) {
            int row = ch >> 5, kc = ch & 31;
            half8 v = *(const half8*)(snb + row * D_ + kc * 8);
            int off = row * 512 + kc * 16;
            off ^= ((off >> 9) & 7) << 4;
            *(half8*)(sst + off) = v;
        }
        __syncthreads();
    }
}

extern "C" void kernel_launch(void* const* d_in, const int* in_sizes, int n_in,
                              void* d_out, int out_size, void* d_ws, size_t ws_size,
                              hipStream_t stream) {
    const float* x  = (const float*)d_in[0];
    const float* Wl = (const float*)d_in[1];
    const float* Wr = (const float*)d_in[2];
    const float* Wb = (const float*)d_in[3];
    const float* Gl = (const float*)d_in[4];
    const float* Gr = (const float*)d_in[5];
    const float* Gb = (const float*)d_in[6];
    float* out = (float*)d_out;
    char* ws = (char*)d_ws;

    _Float16* S0 = (_Float16*)ws;                                   // 2 MB
    _Float16* S1 = (_Float16*)(ws + (size_t)2 * 1024 * 1024);       // 2 MB
    _Float16* WT = (_Float16*)(ws + (size_t)4 * 1024 * 1024);       // 384 KB
    int* bar = (int*)(ws + (size_t)4 * 1024 * 1024 + 393216);       // 8 KB

    prep_wt<<<NG * WC, 256, 0, stream>>>(Wl, Wr, Gl, Gr, WT);
    init_state<<<B_, 256, 0, stream>>>(x, S0, out, bar);

    void* args[] = { &S0, &S1, &WT, (void*)&Wb, (void*)&Gb, &out, &bar };
    hipLaunchCooperativeKernel((const void*)grcnn_persist, dim3(B_ * NG), dim3(NTHR),
                               args, 0, stream);
}

// Round 3
// 1023.330 us; speedup vs baseline: 3.1126x; 3.1126x over previous
//
#include <hip/hip_runtime.h>

// GrCNN: B=32, L=128, D=256, 127 sequential levels.
// Round 3: persistent cooperative kernel, 256 blocks = (b, g).
// Fix vs round 2: NO acquire/release fences (they invalidate/writeback the
// whole per-XCD L2 on gfx950). All cross-block exchange uses RELAXED
// agent-scope uint atomics (coherent at L3), barrier = monotonic counter +
// relaxed poll, ordering by per-wave s_waitcnt vmcnt(0) before the add.

#define B_ 32
#define L_ 128
#define D_ 256
#define K_ 512          // 2*D (left|right concat)
#define NG 8            // column groups
#define GC 32           // central cols per group
#define WC 48           // cols per group incl 16-col gate tile
#define NTHR 512        // 8 waves
#define LOG2E 1.4426950408889634f

typedef _Float16 half8 __attribute__((ext_vector_type(8)));
typedef float f32x4 __attribute__((ext_vector_type(4)));

// ---- prep: build WT[g][WC][K_] fp16 (col j -> 512 k's) ----
__global__ void prep_wt(const float* __restrict__ Wl, const float* __restrict__ Wr,
                        const float* __restrict__ Gl, const float* __restrict__ Gr,
                        _Float16* __restrict__ WT) {
    int g = blockIdx.x / WC;
    int j = blockIdx.x % WC;
    for (int k = threadIdx.x; k < K_; k += 256) {
        float v;
        if (j < GC) {
            int c = g * GC + j;
            v = (k < D_) ? Wl[k * D_ + c] : Wr[(k - D_) * D_ + c];
        } else {
            int jj = j - GC;
            v = 0.f;
            if (jj < 3) v = (k < D_) ? Gl[k * 3 + jj] : Gr[(k - D_) * 3 + jj];
        }
        WT[((size_t)(g * WC + j)) * K_ + k] = (_Float16)v;
    }
}

// ---- init: x -> fp16 state S0, level-0 col max, zero barrier words ----
__global__ void init_state(const float* __restrict__ x, _Float16* __restrict__ S0,
                           float* __restrict__ out, int* __restrict__ bar) {
    int b = blockIdx.x;
    int c = threadIdx.x;  // 256
    if (b == 0 && c < 2 * B_) bar[c * 32] = 0;   // cnt[0..31], gen[0..31]
    float m = -3.4e38f;
    for (int l = 0; l < L_; ++l) {
        float v = x[((size_t)b * L_ + l) * D_ + c];
        S0[((size_t)b * L_ + l) * D_ + c] = (_Float16)v;
        m = fmaxf(m, v);
    }
    out[(size_t)b * L_ * D_ + c] = m;  // out[b][0][c]
}

// LDS: state 129 rows * 512B (swizzled) + W slice 48KB (swizzled) + wave maxes
#define SST_BYTES ((L_ + 1) * D_ * 2)     // 66048
#define WST_BYTES (WC * K_ * 2)           // 49152
#define LDS_BYTES (SST_BYTES + WST_BYTES + 8 * GC * 4)

__global__ __launch_bounds__(NTHR) void grcnn_persist(
    _Float16* __restrict__ S0, _Float16* __restrict__ S1,
    const _Float16* __restrict__ WT, const float* __restrict__ Wb,
    const float* __restrict__ Gb, float* __restrict__ out, int* __restrict__ bar)
{
    __shared__ alignas(16) char lds[LDS_BYTES];
    char* sst = lds;
    char* wst = lds + SST_BYTES;
    float* lmax = (float*)(lds + SST_BYTES + WST_BYTES);  // [8][GC]

    const int tid = threadIdx.x;
    const int b = blockIdx.x & 31, g = blockIdx.x >> 5;  // siblings share blockIdx%32

    // stage W slice once
    const _Float16* wg = WT + (size_t)g * WC * K_;
    for (int ch = tid; ch < WC * K_ / 8; ch += NTHR) {
        int j = ch >> 6, kc = ch & 63;
        half8 v = *(const half8*)(wg + j * K_ + kc * 8);
        int off = j * 1024 + kc * 16;
        off ^= ((off >> 10) & 7) << 4;
        *(half8*)(wst + off) = v;
    }
    // stage full sentence state from S0
    const _Float16* sb0 = S0 + (size_t)b * L_ * D_;
    for (int ch = tid; ch < L_ * 32; ch += NTHR) {
        int row = ch >> 5, kc = ch & 31;
        half8 v = *(const half8*)(sb0 + row * D_ + kc * 8);
        int off = row * 512 + kc * 16;
        off ^= ((off >> 9) & 7) << 4;
        *(half8*)(sst + off) = v;
    }

    const int w = tid >> 6, l = tid & 63;
    const int lr = l & 15, q = l >> 4;
    const int r0 = w * 16;                 // wave's 16-row slab
    const float gb0 = Gb[0], gb1 = Gb[1], gb2 = Gb[2];
    const float wb0 = Wb[g * GC + lr];
    const float wb1 = Wb[g * GC + 16 + lr];
    int* cnt = bar + b * 32;
    int* gen = bar + (B_ + b) * 32;
    __syncthreads();

    for (int t = 0; t < L_ - 1; ++t) {
        const int n = (L_ - 1) - t;        // rows computed this level
        char* snb = (char*)(((t & 1) ? S0 : S1) + (size_t)b * L_ * D_);
        const bool active = (r0 < n);

        f32x4 acc0 = {}, acc1 = {}, acc2 = {};
        if (active) {
            #pragma unroll
            for (int s = 0; s < 16; ++s) {
                const int ko = s * 64 + q * 16;
                int aoff = (r0 + lr) * 512 + ko; aoff ^= ((aoff >> 9) & 7) << 4;
                half8 av = *(const half8*)(sst + aoff);
                const int sw = (lr & 7) << 4;
                half8 b0 = *(const half8*)(wst + ((lr * 1024 + ko) ^ sw));
                half8 b1 = *(const half8*)(wst + (((16 + lr) * 1024 + ko) ^ sw));
                half8 b2 = *(const half8*)(wst + (((32 + lr) * 1024 + ko) ^ sw));
                acc0 = __builtin_amdgcn_mfma_f32_16x16x32_f16(av, b0, acc0, 0, 0, 0);
                acc1 = __builtin_amdgcn_mfma_f32_16x16x32_f16(av, b1, acc1, 0, 0, 0);
                acc2 = __builtin_amdgcn_mfma_f32_16x16x32_f16(av, b2, acc2, 0, 0, 0);
            }
        }

        float vmax0 = -3.4e38f, vmax1 = -3.4e38f;
        _Float16 nh[4][2];
        bool wr[4] = {false, false, false, false};
        if (active) {
            #pragma unroll
            for (int r = 0; r < 4; ++r) {
                const int row = r0 + q * 4 + r;
                float p0 = __shfl(acc2[r], (l & 48) + 0, 64) + gb0;
                float p1 = __shfl(acc2[r], (l & 48) + 1, 64) + gb1;
                float p2 = __shfl(acc2[r], (l & 48) + 2, 64) + gb2;
                if (row < n) {
                    wr[r] = true;
                    float mg = fmaxf(fmaxf(p0, p1), p2);
                    float e0 = exp2f((p0 - mg) * LOG2E);
                    float e1 = exp2f((p1 - mg) * LOG2E);
                    float e2 = exp2f((p2 - mg) * LOG2E);
                    float inv = __builtin_amdgcn_rcpf(e0 + e1 + e2);
                    float g0 = e0 * inv, g1 = e1 * inv, g2 = e2 * inv;
                    {   // nt = 0
                        int c = g * GC + lr;
                        float pre = acc0[r] + wb0;
                        float ex = exp2f(pre * (2.f * LOG2E));
                        float ce = 1.f - 2.f * __builtin_amdgcn_rcpf(ex + 1.f);
                        int lo = row * 512 + c * 2;       lo ^= ((lo >> 9) & 7) << 4;
                        int ro = (row + 1) * 512 + c * 2; ro ^= ((ro >> 9) & 7) << 4;
                        float lv = (float)*(const _Float16*)(sst + lo);
                        float rv = (float)*(const _Float16*)(sst + ro);
                        float nx = g0 * lv + g1 * ce + g2 * rv;
                        nh[r][0] = (_Float16)nx;
                        vmax0 = fmaxf(vmax0, nx);
                    }
                    {   // nt = 1
                        int c = g * GC + 16 + lr;
                        float pre = acc1[r] + wb1;
                        float ex = exp2f(pre * (2.f * LOG2E));
                        float ce = 1.f - 2.f * __builtin_amdgcn_rcpf(ex + 1.f);
                        int lo = row * 512 + c * 2;       lo ^= ((lo >> 9) & 7) << 4;
                        int ro = (row + 1) * 512 + c * 2; ro ^= ((ro >> 9) & 7) << 4;
                        float lv = (float)*(const _Float16*)(sst + lo);
                        float rv = (float)*(const _Float16*)(sst + ro);
                        float nx = g0 * lv + g1 * ce + g2 * rv;
                        nh[r][1] = (_Float16)nx;
                        vmax1 = fmaxf(vmax1, nx);
                    }
                }
            }
        }

        __syncthreads();   // all old-state reads done before in-place update

        if (active) {
            #pragma unroll
            for (int r = 0; r < 4; ++r) if (wr[r]) {
                const int row = r0 + q * 4 + r;
                int c0 = g * GC + lr;
                int o0 = row * 512 + c0 * 2; o0 ^= ((o0 >> 9) & 7) << 4;
                *(_Float16*)(sst + o0) = nh[r][0];
                int o1 = row * 512 + (c0 + 16) * 2; o1 ^= ((o1 >> 9) & 7) << 4;
                *(_Float16*)(sst + o1) = nh[r][1];
            }
        }
        // col-max across the 4 q-groups
        vmax0 = fmaxf(vmax0, __shfl_xor(vmax0, 16, 64));
        vmax0 = fmaxf(vmax0, __shfl_xor(vmax0, 32, 64));
        vmax1 = fmaxf(vmax1, __shfl_xor(vmax1, 16, 64));
        vmax1 = fmaxf(vmax1, __shfl_xor(vmax1, 32, 64));
        if (l < 16) { lmax[w * GC + l] = vmax0; lmax[w * GC + 16 + l] = vmax1; }
        __syncthreads();   // nh in LDS + lmax visible to all

        if (tid < GC) {
            float m = lmax[tid];
            #pragma unroll
            for (int ww = 1; ww < 8; ++ww) m = fmaxf(m, lmax[ww * GC + tid]);
            out[((size_t)b * L_ + (t + 1)) * D_ + g * GC + tid] = m;
        }
        // export own 32-col stripe, rows 0..n-1, as relaxed agent uint atomics (-> L3)
        for (int ch = tid; ch < n * 16; ch += NTHR) {
            int row = ch >> 4, u = ch & 15;
            int off = row * 512 + g * 64 + u * 4;
            int so = off ^ (((off >> 9) & 7) << 4);
            unsigned v = *(const unsigned*)(sst + so);
            __hip_atomic_store((unsigned*)(snb + off), v,
                               __ATOMIC_RELAXED, __HIP_MEMORY_SCOPE_AGENT);
        }
        asm volatile("s_waitcnt vmcnt(0)" ::: "memory");  // per-wave: exports at L3
        __syncthreads();

        if (tid == 0) {
            int prev = __hip_atomic_fetch_add(cnt, 1, __ATOMIC_RELAXED,
                                              __HIP_MEMORY_SCOPE_AGENT);
            if (prev == (t + 1) * NG - 1) {
                __hip_atomic_fetch_add(gen, 1, __ATOMIC_RELAXED,
                                       __HIP_MEMORY_SCOPE_AGENT);
            } else {
                while (__hip_atomic_load(gen, __ATOMIC_RELAXED,
                                         __HIP_MEMORY_SCOPE_AGENT) <= t)
                    __builtin_amdgcn_s_sleep(1);
            }
        }
        __syncthreads();

        // re-stage rows 0..n-1 (all 256 cols) with relaxed agent atomic loads
        for (int ch = tid; ch < n * 128; ch += NTHR) {
            int row = ch >> 7, u = ch & 127;
            unsigned v = __hip_atomic_load((const unsigned*)(snb + row * 512 + u * 4),
                                           __ATOMIC_RELAXED, __HIP_MEMORY_SCOPE_AGENT);
            int off = row * 512 + u * 4;
            off ^= ((off >> 9) & 7) << 4;
            *(unsigned*)(sst + off) = v;
        }
        __syncthreads();
    }
}

extern "C" void kernel_launch(void* const* d_in, const int* in_sizes, int n_in,
                              void* d_out, int out_size, void* d_ws, size_t ws_size,
                              hipStream_t stream) {
    const float* x  = (const float*)d_in[0];
    const float* Wl = (const float*)d_in[1];
    const float* Wr = (const float*)d_in[2];
    const float* Wb = (const float*)d_in[3];
    const float* Gl = (const float*)d_in[4];
    const float* Gr = (const float*)d_in[5];
    const float* Gb = (const float*)d_in[6];
    float* out = (float*)d_out;
    char* ws = (char*)d_ws;

    _Float16* S0 = (_Float16*)ws;                                   // 2 MB
    _Float16* S1 = (_Float16*)(ws + (size_t)2 * 1024 * 1024);       // 2 MB
    _Float16* WT = (_Float16*)(ws + (size_t)4 * 1024 * 1024);       // 384 KB
    int* bar = (int*)(ws + (size_t)4 * 1024 * 1024 + 393216);       // 8 KB

    prep_wt<<<NG * WC, 256, 0, stream>>>(Wl, Wr, Gl, Gr, WT);
    init_state<<<B_, 256, 0, stream>>>(x, S0, out, bar);

    void* args[] = { &S0, &S1, &WT, (void*)&Wb, (void*)&Gb, &out, &bar };
    hipLaunchCooperativeKernel((const void*)grcnn_persist, dim3(B_ * NG), dim3(NTHR),
                               args, 0, stream);
}